// Round 1
// baseline (1781.939 us; speedup 1.0000x reference)
//
#include <hip/hip_runtime.h>
#include <hip/hip_bf16.h>

// RNNClassifier: B=64, T=2048, V=50000, E=256, H=256, O=16
// K1: xh[B,T,H] = emb[x] @ W_ih^T + (b_ih + b_hh)      (parallel GEMM, fp32 VALU)
// K2: h_t = tanh(xh_t + h_{t-1} @ W_hh^T) scanned over T, one WG per batch
//     element (batch chains are independent -> no grid sync), W_hh held in
//     VGPRs (128 floats/thread x 512 threads = 256KB), h ping-pongs in LDS.
//     MLP head fused into K2 epilogue.

#define B_  64
#define T_  2048
#define E_  256
#define H_  256
#define O_  16
#define H2_ 128

__device__ __forceinline__ float tanh_fast(float x) {
  // tanh(x) = 1 - 2/(exp(2x)+1); exact at +/-inf, ~1e-7 abs err in between
  return 1.0f - 2.0f / (__expf(2.0f * x) + 1.0f);
}

// xh element storage: fp32 if workspace fits 128 MiB, else bf16 fallback
__device__ __forceinline__ float xt_load(const float* p) { return *p; }
__device__ __forceinline__ float xt_load(const __hip_bfloat16* p) { return __bfloat162float(*p); }
__device__ __forceinline__ void  xt_store(float* p, float v) { *p = v; }
__device__ __forceinline__ void  xt_store(__hip_bfloat16* p, float v) { *p = __float2bfloat16(v); }

// ---------------------------------------------------------------------------
// K1: gathered GEMM. Grid = B*T/64 tiles of 64 rows; 256 threads.
// A-tile (64 gathered emb rows, 64KB) staged in LDS; W_ih streamed from
// L2 into registers in k-chunks of 32; per-thread micro-tile = 32 rows x
// 2 cols -> 8 fp32 FMAs per ds_read_b128 broadcast (FMA-bound).
// ---------------------------------------------------------------------------
template <typename XT>
__global__ __launch_bounds__(256) void k1_xh(
    const int* __restrict__ x, const float* __restrict__ emb,
    const float* __restrict__ W_ih, const float* __restrict__ b_ih,
    const float* __restrict__ b_hh, XT* __restrict__ xh) {
  __shared__ float A_s[64][256];   // 64 KB -> 2 WGs/CU
  __shared__ int   x_s[64];
  const int  tid = threadIdx.x;
  const long r0  = (long)blockIdx.x * 64;

  if (tid < 64) x_s[tid] = x[r0 + tid];
  __syncthreads();

  {  // stage gathered A tile, coalesced float4 (64 lanes cover one row)
    const int rsub = tid >> 6;         // 0..3
    const int e    = (tid & 63) << 2;  // 0..252
#pragma unroll
    for (int p = 0; p < 16; ++p) {
      const int r = (p << 2) + rsub;
      *(float4*)&A_s[r][e] = *(const float4*)&emb[(long)x_s[r] * E_ + e];
    }
  }
  __syncthreads();

  const int cp = tid & 127;  // columns cp and cp+128
  const int rh = tid >> 7;   // row half: rows rh*32 .. rh*32+31
  float acc0[32], acc1[32];
#pragma unroll
  for (int m = 0; m < 32; ++m) { acc0[m] = 0.f; acc1[m] = 0.f; }

#pragma unroll
  for (int kc = 0; kc < 8; ++kc) {  // K in chunks of 32
    const int k0 = kc << 5;
    float4 wv0[8], wv1[8];
#pragma unroll
    for (int q = 0; q < 8; ++q) {   // W rows cp / cp+128, contiguous in k
      wv0[q] = *(const float4*)&W_ih[cp * E_ + k0 + 4 * q];
      wv1[q] = *(const float4*)&W_ih[(cp + 128) * E_ + k0 + 4 * q];
    }
#pragma unroll
    for (int m = 0; m < 32; ++m) {
      const int mm = (rh << 5) + m;
#pragma unroll
      for (int q = 0; q < 8; ++q) {
        const float4 a = *(const float4*)&A_s[mm][k0 + 4 * q];  // broadcast
        acc0[m] += a.x * wv0[q].x + a.y * wv0[q].y + a.z * wv0[q].z + a.w * wv0[q].w;
        acc1[m] += a.x * wv1[q].x + a.y * wv1[q].y + a.z * wv1[q].z + a.w * wv1[q].w;
      }
    }
  }

  const float bias0 = b_ih[cp] + b_hh[cp];
  const float bias1 = b_ih[cp + 128] + b_hh[cp + 128];
#pragma unroll
  for (int m = 0; m < 32; ++m) {
    const long r = r0 + (rh << 5) + m;
    xt_store(&xh[r * H_ + cp],       acc0[m] + bias0);
    xt_store(&xh[r * H_ + cp + 128], acc1[m] + bias1);
  }
}

// ---------------------------------------------------------------------------
// K2: sequential scan + fused MLP head. Grid = 64 (one WG per batch chain),
// 512 threads = 8 waves. wave w owns j in [32w, 32w+32); lane l owns
// neurons {l, l+64, l+128, l+192}. W_hh chunk lives in 128 VGPRs/thread.
// h ping-pongs in LDS; 8-way partial reduce through LDS; 2 barriers/step.
// ---------------------------------------------------------------------------
template <typename XT>
__global__ __launch_bounds__(512) void k2_rnn(
    const XT* __restrict__ xh, const float* __restrict__ W_hh,
    const float* __restrict__ fc1_w, const float* __restrict__ fc1_b,
    const float* __restrict__ fc2_w, const float* __restrict__ fc2_b,
    float* __restrict__ out) {
  __shared__ float h_s[2][H_];
  __shared__ float part[8][H_];
  __shared__ float hid_s[H2_];

  const int tid   = threadIdx.x;
  const int wave  = tid >> 6;
  const int lane  = tid & 63;
  const int jbase = wave << 5;  // this wave's j-chunk
  const int b     = blockIdx.x;
  const XT* xb    = xh + (size_t)b * T_ * H_;

  // W_hh fragment into registers: w4[m][q] = W_hh[(64m+lane)][jbase+4q..+3]
  float4 w4[4][8];
#pragma unroll
  for (int m = 0; m < 4; ++m)
#pragma unroll
    for (int q = 0; q < 8; ++q)
      w4[m][q] = *(const float4*)&W_hh[(m * 64 + lane) * H_ + jbase + 4 * q];

  if (tid < H_) h_s[0][tid] = 0.f;  // h0 = 0
  __syncthreads();

  for (int t = 0; t < T_; ++t) {
    const int cur = t & 1, nxt = cur ^ 1;
    float xt = 0.f;
    if (tid < H_) xt = xt_load(&xb[(size_t)t * H_ + tid]);  // overlaps FMA loop

    float a0 = 0.f, a1 = 0.f, a2 = 0.f, a3 = 0.f;
    const float* hb = h_s[cur];
#pragma unroll
    for (int q = 0; q < 8; ++q) {
      const float4 hv = *(const float4*)&hb[jbase + 4 * q];  // wave-uniform broadcast
      a0 += w4[0][q].x * hv.x + w4[0][q].y * hv.y + w4[0][q].z * hv.z + w4[0][q].w * hv.w;
      a1 += w4[1][q].x * hv.x + w4[1][q].y * hv.y + w4[1][q].z * hv.z + w4[1][q].w * hv.w;
      a2 += w4[2][q].x * hv.x + w4[2][q].y * hv.y + w4[2][q].z * hv.z + w4[2][q].w * hv.w;
      a3 += w4[3][q].x * hv.x + w4[3][q].y * hv.y + w4[3][q].z * hv.z + w4[3][q].w * hv.w;
    }
    part[wave][lane]       = a0;
    part[wave][64 + lane]  = a1;
    part[wave][128 + lane] = a2;
    part[wave][192 + lane] = a3;
    __syncthreads();

    if (tid < H_) {
      float s = xt;
#pragma unroll
      for (int w = 0; w < 8; ++w) s += part[w][tid];
      h_s[nxt][tid] = tanh_fast(s);
    }
    __syncthreads();
  }

  // fused MLP head; T even -> final h is in h_s[0]
  const float* hf = h_s[0];
  if (tid < H2_) {
    float s = fc1_b[tid];
#pragma unroll
    for (int q = 0; q < 64; ++q) {
      const float4 w = *(const float4*)&fc1_w[tid * H_ + 4 * q];
      const float4 h = *(const float4*)&hf[4 * q];
      s += w.x * h.x + w.y * h.y + w.z * h.z + w.w * h.w;
    }
    hid_s[tid] = fmaxf(s, 0.f);
  }
  __syncthreads();
  if (tid < O_) {
    float s = fc2_b[tid];
#pragma unroll
    for (int q = 0; q < 32; ++q) {
      const float4 w = *(const float4*)&fc2_w[tid * H2_ + 4 * q];
      const float4 h = *(const float4*)&hid_s[4 * q];
      s += w.x * h.x + w.y * h.y + w.z * h.z + w.w * h.w;
    }
    out[b * O_ + tid] = s;
  }
}

extern "C" void kernel_launch(void* const* d_in, const int* in_sizes, int n_in,
                              void* d_out, int out_size, void* d_ws, size_t ws_size,
                              hipStream_t stream) {
  const int*   x     = (const int*)d_in[0];
  const float* emb   = (const float*)d_in[1];
  const float* W_ih  = (const float*)d_in[2];
  const float* W_hh  = (const float*)d_in[3];
  const float* b_ih  = (const float*)d_in[4];
  const float* b_hh  = (const float*)d_in[5];
  const float* fc1_w = (const float*)d_in[6];
  const float* fc1_b = (const float*)d_in[7];
  const float* fc2_w = (const float*)d_in[8];
  const float* fc2_b = (const float*)d_in[9];
  float* out = (float*)d_out;

  const dim3 g1(B_ * T_ / 64), blk1(256);
  const dim3 g2(B_), blk2(512);
  const size_t need_f32 = (size_t)B_ * T_ * H_ * sizeof(float);  // 128 MiB

  if (ws_size >= need_f32) {
    float* xh = (float*)d_ws;
    k1_xh<float><<<g1, blk1, 0, stream>>>(x, emb, W_ih, b_ih, b_hh, xh);
    k2_rnn<float><<<g2, blk2, 0, stream>>>(xh, W_hh, fc1_w, fc1_b, fc2_w, fc2_b, out);
  } else {  // bf16 xh fallback (64 MiB)
    __hip_bfloat16* xh = (__hip_bfloat16*)d_ws;
    k1_xh<__hip_bfloat16><<<g1, blk1, 0, stream>>>(x, emb, W_ih, b_ih, b_hh, xh);
    k2_rnn<__hip_bfloat16><<<g2, blk2, 0, stream>>>(xh, W_hh, fc1_w, fc1_b, fc2_w, fc2_b, out);
  }
}